// Round 5
// baseline (26.779 us; speedup 1.0000x reference)
//
#include <hip/hip_runtime.h>
#include <math.h>

#define TT 200
#define UU 200
#define VV 512
#define BB 8
#define NEGF (-1e30f)
#define PSTRIDE 212      // dwords per P2 row in ws
#define ROWS_PER 25      // t-rows per stage-1 slice

// ws float layout:
//   P2   [BB*16][PSTRIDE] : offset 0      (8*16*212 = 27136)
//   maxE [BB][200]        : offset 27136  (1600)
//   base [BB]             : offset 28736  (8)
#define WS_P2   0
#define WS_MAXE 27136
#define WS_BASE 28736

// ---- DPP helpers (VALU pipe cross-lane) ----
#define DPP_QUAD_XOR1       0xB1
#define DPP_QUAD_XOR2       0x4E
#define DPP_ROW_SHL1        0x101
#define DPP_ROW_SHR1        0x111
#define DPP_ROW_SHR2        0x112
#define DPP_ROW_SHR4        0x114
#define DPP_ROW_SHR8        0x118
#define DPP_ROW_MIRROR      0x140
#define DPP_ROW_HALF_MIRROR 0x141

template<int CTRL, bool ZERO>
__device__ __forceinline__ float fdpp(float src) {
    return __int_as_float(__builtin_amdgcn_update_dpp(
        __float_as_int(src), __float_as_int(src), CTRL, 0xF, 0xF, ZERO));
}

__device__ __forceinline__ float max16(float x) {
    x = fmaxf(x, fdpp<DPP_QUAD_XOR1, true>(x));
    x = fmaxf(x, fdpp<DPP_QUAD_XOR2, true>(x));
    x = fmaxf(x, fdpp<DPP_ROW_HALF_MIRROR, true>(x));
    x = fmaxf(x, fdpp<DPP_ROW_MIRROR, true>(x));
    return x;
}

__device__ __forceinline__ float sum16(float x) {
    x += fdpp<DPP_QUAD_XOR1, true>(x);
    x += fdpp<DPP_QUAD_XOR2, true>(x);
    x += fdpp<DPP_ROW_HALF_MIRROR, true>(x);
    x += fdpp<DPP_ROW_MIRROR, true>(x);
    return x;
}

__device__ __forceinline__ float scan16(float x) {
    x += fdpp<DPP_ROW_SHR1, true>(x);
    x += fdpp<DPP_ROW_SHR2, true>(x);
    x += fdpp<DPP_ROW_SHR4, true>(x);
    x += fdpp<DPP_ROW_SHR8, true>(x);
    return x;
}

// ---- Stage 1: gather + Ce scans + step factors, 8 slices x 8 samples ----
__global__ __launch_bounds__(256) void rnnt_stage1(
    const float* __restrict__ lp,
    const int* __restrict__ targets,
    const int* __restrict__ logit_lengths,
    const int* __restrict__ target_lengths,
    float* __restrict__ ws)
{
    __shared__ float Ls[26][16];
    __shared__ float Ps[26][16];
    __shared__ float Ce[26 * 16];
    __shared__ int   tgt_s[UU];

    const int blk   = blockIdx.x;
    const int b     = blk >> 3;
    const int slice = blk & 7;
    const int t0    = slice * ROWS_PER;
    const int rlo   = (slice == 0) ? 0 : t0 - 1;     // extra row for Ce[t-1]
    const int nrows = ROWS_PER + (slice ? 1 : 0);
    const int tid   = threadIdx.x;
    const float LOG2E = 1.4426950408889634f;

    const float* __restrict__ lpb = lp + (size_t)b * TT * UU * VV;

    if (tid < UU) tgt_s[tid] = targets[b * UU + tid];
    __syncthreads();

    // gather nrows*24 (<=624) band values
    #pragma unroll
    for (int it = 0; it < 3; ++it) {
        int idx  = tid + it * 256;
        bool live = idx < nrows * 24;
        int tl = idx / 24;
        int r  = idx - tl * 24;
        bool isL = r < 12;
        int l = isL ? r : r - 12;
        int t = rlo + tl;
        int u = t + l + (isL ? -5 : -4);
        bool ok = live && (u >= 0) && (u < UU);
        float val = 0.0f;
        if (ok) {
            int v = isL ? tgt_s[u] : 0;
            val = lpb[((size_t)t * UU + u) * VV + v] * LOG2E;
        }
        if (live) {
            if (isL) Ls[tl][l] = val;
            else     Ps[tl][l] = val;
        }
    }
    __syncthreads();

    const int g = tid >> 4;
    const int l = tid & 15;

    // Ce scans (per-row, independent)
    for (int tl = g; tl < nrows; tl += 16) {
        float lv = (l < 12) ? Ls[tl][l] : 0.0f;
        float cin = scan16(lv);
        Ce[tl * 16 + l] = cin - lv;
    }
    __syncthreads();

    // step factors P2[t], normalizers maxE[t], for t in [max(t0,1), t0+25)
    for (int tl = 1 + g; tl < nrows; tl += 16) {
        int t = rlo + tl;
        int u = t - 5 + l;
        bool vcur  = (l <= 10) && (u >= 0) && (u < UU);
        bool vprev = (l + 1 <= 10) && (u >= 0) && (u < UU);  // (t-1)-5+(l+1) == u
        float cpn = Ce[(tl - 1) * 16 + ((l + 1) & 15)];
        float ps  = (l < 12) ? Ps[tl - 1][l] : 0.0f;
        float cec = Ce[tl * 16 + l];
        float E = vcur ? (cpn + ps - cec) : NEGF;
        float mE = max16(E);
        float p2 = __builtin_amdgcn_exp2f(E - mE);
        if (!vprev) p2 = 0.0f;
        ws[WS_P2 + ((size_t)(b * 16 + l)) * PSTRIDE + (t - 1)] = p2;
        if (l == 0) ws[WS_MAXE + b * 200 + t] = mE;
    }

    // base scalar: Ce at (tlen, lstar) — owned by the slice containing tlen
    const int tlen = logit_lengths[b];
    const int ulen = target_lengths[b];
    if (tid == 0 && tlen >= t0 && tlen < t0 + ROWS_PER) {
        int lstar = ulen - tlen + 5;
        ws[WS_BASE + b] = Ce[(tlen - rlo) * 16 + lstar];
    }
}

// ---- Stage 2: 8 parallel DPs (16-lane groups), final mean, single store ----
__global__ __launch_bounds__(128) void rnnt_stage2(
    const int* __restrict__ logit_lengths,
    const int* __restrict__ target_lengths,
    const float* __restrict__ ws,
    float* __restrict__ out)
{
    __shared__ float red[2];
    const int tid = threadIdx.x;
    const int s = tid >> 4;    // sample 0..7
    const int l = tid & 15;

    const int tlen = logit_lengths[s];
    const int ulen = target_lengths[s];

    // F = sum maxE[s][1..tlen]  (off the DP chain; hidden under DP)
    float facc = 0.0f;
    const float* __restrict__ me = ws + WS_MAXE + s * 200;
    for (int t = 1 + l; t <= tlen; t += 16) facc += me[t];
    float F = sum16(facc);

    const float* __restrict__ rowp = ws + WS_P2 + (size_t)(s * 16 + l) * PSTRIDE;

    float Q = (l >= 5 && l <= 10) ? 1.0f : 0.0f;
    int Msum = 0;
    const int nfull = tlen >> 3;

#define STEP(PV) do {                                \
        float sq_ = fdpp<DPP_ROW_SHL1, true>(Q);     \
        Q = scan16(sq_ * (PV));                      \
    } while (0)

    float4 A0 = *(const float4*)(rowp + 0);
    float4 B0 = *(const float4*)(rowp + 4);
    float4 A1 = *(const float4*)(rowp + 8);
    float4 B1 = *(const float4*)(rowp + 12);

    for (int c = 0; c < nfull; ++c) {
        float4 A2 = *(const float4*)(rowp + 8 * c + 16);
        float4 B2 = *(const float4*)(rowp + 8 * c + 20);
        STEP(A0.x); STEP(A0.y); STEP(A0.z); STEP(A0.w);
        STEP(B0.x); STEP(B0.y); STEP(B0.z); STEP(B0.w);
        // per-group exact pow2 renorm (row max; Msum + log2(Q) invariant)
        float mq = max16(Q);
        int ex;
        frexpf(mq, &ex);
        Q = ldexpf(Q, -ex);
        Msum += ex;
        A0 = A1; B0 = B1; A1 = A2; B1 = B2;
    }
    // tail: r in [0,7] remaining steps from chunk nfull (now in A0/B0).
    // tlen is per-group -> divergence is exec-masked; DPP rows stay coherent.
    int r = tlen & 7;
    if (r >= 1) STEP(A0.x);
    if (r >= 2) STEP(A0.y);
    if (r >= 3) STEP(A0.z);
    if (r >= 4) STEP(A0.w);
    if (r >= 5) STEP(B0.x);
    if (r >= 6) STEP(B0.y);
    if (r >= 7) STEP(B0.z);
#undef STEP

    // alpha[tlen][ulen] = base + F + Msum + log2(Q) at lane lstar
    int lstar = ulen - tlen + 5;
    float contrib = 0.0f;
    if (l == lstar)
        contrib = ws[WS_BASE + s] + F + (float)Msum + __builtin_amdgcn_logf(Q);
    #pragma unroll
    for (int d = 32; d; d >>= 1) contrib += __shfl_xor(contrib, d, 64);
    if ((tid & 63) == 0) red[tid >> 6] = contrib;
    __syncthreads();
    if (tid == 0) {
        const float LN2 = 0.6931471805599453f;
        out[0] = -(red[0] + red[1]) * (LN2 / (float)BB);
    }
}

extern "C" void kernel_launch(void* const* d_in, const int* in_sizes, int n_in,
                              void* d_out, int out_size, void* d_ws, size_t ws_size,
                              hipStream_t stream) {
    const float* lp  = (const float*)d_in[0];
    const int* tgt   = (const int*)d_in[1];
    const int* llen  = (const int*)d_in[2];
    const int* tlen  = (const int*)d_in[3];
    float* out = (float*)d_out;
    float* wsf = (float*)d_ws;
    (void)in_sizes; (void)n_in; (void)out_size; (void)ws_size;

    rnnt_stage1<<<dim3(BB * 8), 256, 0, stream>>>(lp, tgt, llen, tlen, wsf);
    rnnt_stage2<<<dim3(1), 128, 0, stream>>>(llen, tlen, wsf, out);
}